// Round 8
// baseline (678.636 us; speedup 1.0000x reference)
//
#include <hip/hip_runtime.h>
#include <stdint.h>

// WL refinement step: hash rows -> XCD-partitioned two-phase edge binning ->
// per-bucket LDS multiset accumulation (fused node-hash; 2048-node buckets for
// ~2 blocks/CU occupancy) -> first-appearance contiguous relabel.
// All int64 arithmetic wraps (matches JAX int64).

#define KC1 6364136223846793005ULL
#define KC2 1442695040888963407ULL
#define KC3 2862933555777941757ULL
#define KC4 3202034522624059733ULL
#define KPT 1000003ULL

#define TBL_BITS 21
#define TBL (1u << TBL_BITS)
#define TMASK (TBL - 1u)
#define KEMPTY 0xFFFFFFFFFFFFFFFFULL
#define KREMAP 0x0123456789ABCDEFULL

// binning: 2048 nodes per bucket (dl=11 bits, src=20 bits -> 32-bit record)
#define BK_SHIFT 11
#define BK_NODES 2048
#define NBK_MAX 512
// 8 partitions (one per XCD via blockIdx&7) -> no cache line written by two XCDs
#define NPART 8
// per (part,bucket) capacity: mean ~4090, sigma ~64, +10 sigma, 64-multiple
#define PCAP 4736u
// global overflow list (statistically never used; correctness backstop)
#define OVFCAP 65536u

typedef int iv4 __attribute__((ext_vector_type(4)));

__device__ __forceinline__ uint64_t mix64(uint64_t h, uint64_t a, uint64_t b) {
    h *= a;
    h ^= (uint64_t)(((int64_t)h) >> 31);   // arithmetic shift, like jnp int64
    h *= b;
    h ^= (uint64_t)(((int64_t)h) >> 29);
    return h;
}

__device__ __forceinline__ uint32_t tslot(uint64_t k) {
    return (uint32_t)((k * 0x9E3779B97F4A7C15ULL) >> (64 - TBL_BITS));
}

// 1. lab[i] = mix(poly(x[i,:]), C1, C2)
__global__ void k_lab(const int* __restrict__ x, uint64_t* __restrict__ lab, int N, int F) {
    int i = blockIdx.x * blockDim.x + threadIdx.x;
    if (i >= N) return;
    const int* row = x + (size_t)i * (size_t)F;
    uint64_t l = 0;
    for (int j = 0; j < F; ++j) l = l * KPT + (uint64_t)(int64_t)row[j];
    lab[i] = mix64(l, KC1, KC2);
}

// 2a. two-phase binning (count, reserve, place) into per-(partition,bucket)
//     segments; partition = blockIdx&7 keeps each segment XCD-private.
//     256 blocks (1/CU) keeps the partial-line write frontier tiny & L2-resident.
__global__ __launch_bounds__(1024)
void k_scatter(const int* __restrict__ ei, uint32_t* __restrict__ binned,
               uint32_t* __restrict__ cursor, unsigned long long* __restrict__ ovf,
               unsigned int* __restrict__ ovf_cnt, int E, int NBK, int chunk) {
    __shared__ uint32_t lcnt[NBK_MAX];
    __shared__ uint32_t lbase[NBK_MAX];
    const int part = blockIdx.x & (NPART - 1);
    const int b0 = blockIdx.x * chunk;
    const int b1 = min(E, b0 + chunk);
    if (b0 >= b1) return;
    for (int t = threadIdx.x; t < NBK; t += blockDim.x) lcnt[t] = 0;
    __syncthreads();
    // ---- phase 1: count dst buckets (dst stream only, nt int4)
    for (int base = b0 + threadIdx.x * 4; base < b1; base += blockDim.x * 4) {
        if (base + 4 <= b1) {
            iv4 d4 = __builtin_nontemporal_load((const iv4*)(ei + (size_t)E + base));
            atomicAdd(&lcnt[(uint32_t)d4.x >> BK_SHIFT], 1u);
            atomicAdd(&lcnt[(uint32_t)d4.y >> BK_SHIFT], 1u);
            atomicAdd(&lcnt[(uint32_t)d4.z >> BK_SHIFT], 1u);
            atomicAdd(&lcnt[(uint32_t)d4.w >> BK_SHIFT], 1u);
        } else {
            for (int j = 0; j < b1 - base; ++j)
                atomicAdd(&lcnt[(uint32_t)ei[(size_t)E + base + j] >> BK_SHIFT], 1u);
        }
    }
    __syncthreads();
    // ---- reserve per-(part,bucket) ranges
    for (int t = threadIdx.x; t < NBK; t += blockDim.x) {
        uint32_t c = lcnt[t];
        lbase[t] = c ? atomicAdd(&cursor[part * NBK + t], c) : 0u;
        lcnt[t] = 0;
    }
    __syncthreads();
    // ---- phase 2: place records
    for (int base = b0 + threadIdx.x * 4; base < b1; base += blockDim.x * 4) {
        int ss[4], dd[4], m;
        if (base + 4 <= b1) {
            iv4 s4 = __builtin_nontemporal_load((const iv4*)(ei + base));
            iv4 d4 = __builtin_nontemporal_load((const iv4*)(ei + (size_t)E + base));
            ss[0]=s4.x; ss[1]=s4.y; ss[2]=s4.z; ss[3]=s4.w;
            dd[0]=d4.x; dd[1]=d4.y; dd[2]=d4.z; dd[3]=d4.w;
            m = 4;
        } else {
            m = b1 - base;
            for (int j = 0; j < m; ++j) {
                ss[j] = ei[base + j];
                dd[j] = ei[(size_t)E + base + j];
            }
        }
        for (int j = 0; j < m; ++j) {
            uint32_t bk = (uint32_t)dd[j] >> BK_SHIFT;
            uint32_t rec = ((uint32_t)(dd[j] & (BK_NODES - 1)) << 20) | (uint32_t)ss[j];
            uint32_t l = atomicAdd(&lcnt[bk], 1u);
            uint32_t idx = lbase[bk] + l;
            if (idx < PCAP) {
                binned[((size_t)part * NBK + bk) * PCAP + idx] = rec;
            } else {
                unsigned int o = atomicAdd(ovf_cnt, 1u);
                if (o < OVFCAP) ovf[o] = ((unsigned long long)bk << 32) | rec;
            }
        }
    }
}

// 2b. per-bucket LDS multiset accumulation over 8 partition segments +
//     fused node-hash: hh = mix(lab*C3 + s1, C1,C2) ^ mix(s2 + lab, C3,C4)
__global__ __launch_bounds__(1024)
void k_accum(const uint32_t* __restrict__ binned, const uint32_t* __restrict__ cursor,
             const unsigned long long* __restrict__ ovf, const unsigned int* __restrict__ ovf_cnt,
             const uint64_t* __restrict__ lab, uint64_t* __restrict__ hh, int N, int NBK) {
    __shared__ unsigned long long s1[BK_NODES];
    __shared__ unsigned long long s2[BK_NODES];
    int b = blockIdx.x;
    for (int t = threadIdx.x; t < BK_NODES; t += blockDim.x) { s1[t] = 0ULL; s2[t] = 0ULL; }
    __syncthreads();
    for (int p = 0; p < NPART; ++p) {
        uint32_t cnt = cursor[p * NBK + b];
        if (cnt > PCAP) cnt = PCAP;
        const uint32_t* seg = binned + ((size_t)p * NBK + b) * PCAP;
        for (uint32_t i = threadIdx.x * 4; i < cnt; i += blockDim.x * 4) {
            uint32_t recs[4];
            int m;
            if (i + 4 <= cnt) {
                iv4 r4 = __builtin_nontemporal_load((const iv4*)(seg + i));
                recs[0]=(uint32_t)r4.x; recs[1]=(uint32_t)r4.y;
                recs[2]=(uint32_t)r4.z; recs[3]=(uint32_t)r4.w;
                m = 4;
            } else {
                m = (int)(cnt - i);
                for (int j = 0; j < m; ++j) recs[j] = seg[i + j];
            }
            for (int j = 0; j < m; ++j) {
                uint64_t nl = lab[recs[j] & 0xFFFFFu];
                uint32_t dl = recs[j] >> 20;
                atomicAdd(&s1[dl], (unsigned long long)mix64(nl, KC1, KC2));
                atomicAdd(&s2[dl], (unsigned long long)mix64(nl, KC3, KC4));
            }
        }
    }
    // overflow sweep (normally ovf_cnt == 0)
    uint32_t oc = *ovf_cnt;
    if (oc > OVFCAP) oc = OVFCAP;
    for (uint32_t i = threadIdx.x; i < oc; i += blockDim.x) {
        unsigned long long r = ovf[i];
        if ((uint32_t)(r >> 32) == (uint32_t)b) {
            uint32_t rec = (uint32_t)r;
            uint64_t nl = lab[rec & 0xFFFFFu];
            uint32_t dl = rec >> 20;
            atomicAdd(&s1[dl], (unsigned long long)mix64(nl, KC1, KC2));
            atomicAdd(&s2[dl], (unsigned long long)mix64(nl, KC3, KC4));
        }
    }
    __syncthreads();
    int node0 = b << BK_SHIFT;
    for (int t = threadIdx.x; t < BK_NODES; t += blockDim.x) {
        int node = node0 + t;
        if (node < N) {
            uint64_t l = lab[node];
            hh[node] = mix64(l * KC3 + (uint64_t)s1[t], KC1, KC2)
                     ^ mix64((uint64_t)s2[t] + l, KC3, KC4);
        }
    }
}

// 4a. hash-table insert: claim slot by key, atomicMin the first-occurrence index
__global__ void k_insert(const uint64_t* __restrict__ h, unsigned long long* __restrict__ keys,
                         unsigned int* __restrict__ vals, int N) {
    int i = blockIdx.x * blockDim.x + threadIdx.x;
    if (i >= N) return;
    uint64_t k = h[i];
    if (k == KEMPTY) k = KREMAP;
    uint32_t slot = tslot(k) & TMASK;
    for (;;) {
        unsigned long long prev = atomicCAS(&keys[slot], KEMPTY, (unsigned long long)k);
        if (prev == KEMPTY || prev == (unsigned long long)k) {
            atomicMin(&vals[slot], (unsigned int)i);
            break;
        }
        slot = (slot + 1u) & TMASK;
    }
}

// 4b+4c fused: lookup rep (min index of my group), flag = (rep==i), and
//     per-1024-block inclusive scan of flags + block sums, in one kernel.
__global__ __launch_bounds__(1024)
void k_lookup_scan(const uint64_t* __restrict__ h, const unsigned long long* __restrict__ keys,
                   const unsigned int* __restrict__ vals, unsigned int* __restrict__ rep,
                   int* __restrict__ incl, int* __restrict__ bsums, int N) {
    __shared__ int sm[1024];
    int tid = threadIdx.x;
    int i = blockIdx.x * 1024 + tid;
    int v = 0;
    if (i < N) {
        uint64_t k = h[i];
        if (k == KEMPTY) k = KREMAP;
        uint32_t slot = tslot(k) & TMASK;
        while (keys[slot] != (unsigned long long)k) slot = (slot + 1u) & TMASK;
        unsigned int r = vals[slot];
        rep[i] = r;
        v = (r == (unsigned int)i) ? 1 : 0;
    }
    sm[tid] = v;
    __syncthreads();
    for (int off = 1; off < 1024; off <<= 1) {
        int t = (tid >= off) ? sm[tid - off] : 0;
        __syncthreads();
        sm[tid] += t;
        __syncthreads();
    }
    if (i < N) incl[i] = sm[tid];
    if (tid == 1023) bsums[blockIdx.x] = sm[1023];
}

// 4d. exclusive scan of block sums (NB <= 1024, single block)
__global__ void k_scan2(const int* __restrict__ bsums, int* __restrict__ boffs, int NB) {
    __shared__ int sm[1024];
    int tid = threadIdx.x;
    int v = (tid < NB) ? bsums[tid] : 0;
    sm[tid] = v;
    __syncthreads();
    for (int off = 1; off < 1024; off <<= 1) {
        int t = (tid >= off) ? sm[tid - off] : 0;
        __syncthreads();
        sm[tid] += t;
        __syncthreads();
    }
    if (tid < NB) boffs[tid] = sm[tid] - v;  // exclusive
}

// 5. out[i] = exclusive-prefix-of-flags at rep[i]
__global__ void k_final(const unsigned int* __restrict__ rep, const int* __restrict__ incl,
                        const int* __restrict__ boffs, int* __restrict__ out, int N) {
    int i = blockIdx.x * blockDim.x + threadIdx.x;
    if (i >= N) return;
    unsigned int r = rep[i];
    out[i] = incl[r] + boffs[r >> 10] - 1;
}

extern "C" void kernel_launch(void* const* d_in, const int* in_sizes, int n_in,
                              void* d_out, int out_size, void* d_ws, size_t ws_size,
                              hipStream_t stream) {
    const int* x  = (const int*)d_in[0];
    const int* ei = (const int*)d_in[1];
    int N = out_size;
    int F = in_sizes[0] / N;
    int E = in_sizes[1] / 2;
    int* out = (int*)d_out;

    int NBK = (N + BK_NODES - 1) >> BK_SHIFT;  // 489 for N=1e6

    // workspace layout (16B-aligned pieces); ~90.7 MB total
    char* w = (char*)d_ws;
    uint64_t* lab = (uint64_t*)w;                        w += (size_t)N * 8;
    uint64_t* hh  = (uint64_t*)w;                        w += (size_t)N * 8;
    uint32_t* cursor = (uint32_t*)w;                     w += (size_t)NPART * NBK_MAX * 4;
    unsigned int* ovf_cnt = (unsigned int*)w;            w += 16;
    unsigned long long* ovf = (unsigned long long*)w;    w += (size_t)OVFCAP * 8;
    uint32_t* binned = (uint32_t*)w;                     // NPART*NBK*PCAP*4 (~74.1 MB)
    // keys/vals/rep/incl dead until after k_accum -> alias the binned region
    char* a = (char*)binned;
    unsigned long long* keys = (unsigned long long*)a;   a += (size_t)TBL * 8;
    unsigned int* vals = (unsigned int*)a;               a += (size_t)TBL * 4;   // contiguous w/ keys
    unsigned int* rep = (unsigned int*)a;                a += (size_t)N * 4;
    int* incl = (int*)a;                                 a += (size_t)N * 4;
    int* bsums = (int*)a;                                a += 1024 * 4;
    int* boffs = (int*)a;                                a += 1024 * 4;

    int nb = (N + 255) / 256;
    int NB = (N + 1023) / 1024;
    int SCB = 256;                                // 1 block/CU, part = blockIdx&7
    int chunk = ((E + SCB - 1) / SCB + 3) & ~3;   // 62500 for E=16M

    (void)hipMemsetAsync(cursor, 0, (size_t)NPART * NBK_MAX * 4 + 16, stream);  // + ovf_cnt
    k_lab<<<nb, 256, 0, stream>>>(x, lab, N, F);
    k_scatter<<<SCB, 1024, 0, stream>>>(ei, binned, cursor, ovf, ovf_cnt, E, NBK, chunk);
    k_accum<<<NBK, 1024, 0, stream>>>(binned, cursor, ovf, ovf_cnt, lab, hh, N, NBK);
    // binned is dead from here; init the aliased hash table (keys+vals both 0xFF)
    (void)hipMemsetAsync(keys, 0xFF, (size_t)TBL * 12, stream);
    k_insert<<<nb, 256, 0, stream>>>(hh, keys, vals, N);
    k_lookup_scan<<<NB, 1024, 0, stream>>>(hh, keys, vals, rep, incl, bsums, N);
    k_scan2<<<1, 1024, 0, stream>>>(bsums, boffs, NB);
    k_final<<<nb, 256, 0, stream>>>(rep, incl, boffs, out, N);
}

// Round 9
// 547.833 us; speedup vs baseline: 1.2388x; 1.2388x over previous
//
#include <hip/hip_runtime.h>
#include <stdint.h>

// WL refinement step: hash rows -> XCD-partitioned two-phase edge binning ->
// per-bucket LDS multiset accumulation with FUSED node-hash + hash-table
// insert (single-u64-slot table, per-node slot memo) -> probe-free lookup ->
// first-appearance contiguous relabel. All int64 arithmetic wraps (JAX int64).

#define KC1 6364136223846793005ULL
#define KC2 1442695040888963407ULL
#define KC3 2862933555777941757ULL
#define KC4 3202034522624059733ULL
#define KPT 1000003ULL

#define TBL_BITS 21
#define TBL (1u << TBL_BITS)
#define TMASK (TBL - 1u)
#define KEMPTY 0xFFFFFFFFFFFFFFFFULL
#define SIGMASK 0xFFFFFFFFFFF00000ULL   // high 44 bits = signature, low 20 = node idx

// binning: 4096 nodes per bucket (dl=12 bits, src=20 bits -> 32-bit record)
#define BK_SHIFT 12
#define BK_NODES 4096
#define NBK_MAX 256
// 8 partitions (one per XCD via blockIdx&7) -> no cache line written by two XCDs
#define NPART 8
// per (part,bucket) capacity: mean ~8163, sigma ~90, +3.9 sigma, 64-multiple
// (rare overflow is handled exactly by the ovf list)
#define PCAP 8512u
// global overflow list (correctness backstop)
#define OVFCAP 16384u

typedef int iv4 __attribute__((ext_vector_type(4)));

__device__ __forceinline__ uint64_t mix64(uint64_t h, uint64_t a, uint64_t b) {
    h *= a;
    h ^= (uint64_t)(((int64_t)h) >> 31);   // arithmetic shift, like jnp int64
    h *= b;
    h ^= (uint64_t)(((int64_t)h) >> 29);
    return h;
}

__device__ __forceinline__ uint32_t tslot(uint64_t k) {
    return (uint32_t)((k * 0x9E3779B97F4A7C15ULL) >> (64 - TBL_BITS));
}

// 1. lab[i] = mix(poly(x[i,:]), C1, C2)
__global__ void k_lab(const int* __restrict__ x, uint64_t* __restrict__ lab, int N, int F) {
    int i = blockIdx.x * blockDim.x + threadIdx.x;
    if (i >= N) return;
    const int* row = x + (size_t)i * (size_t)F;
    uint64_t l = 0;
    for (int j = 0; j < F; ++j) l = l * KPT + (uint64_t)(int64_t)row[j];
    lab[i] = mix64(l, KC1, KC2);
}

// 2a. two-phase binning (count, reserve, place) into per-(partition,bucket)
//     segments; partition = blockIdx&7 keeps each segment XCD-private.
__global__ __launch_bounds__(1024)
void k_scatter(const int* __restrict__ ei, uint32_t* __restrict__ binned,
               uint32_t* __restrict__ cursor, unsigned long long* __restrict__ ovf,
               unsigned int* __restrict__ ovf_cnt, int E, int NBK, int chunk) {
    __shared__ uint32_t lcnt[NBK_MAX];
    __shared__ uint32_t lbase[NBK_MAX];
    const int part = blockIdx.x & (NPART - 1);
    const int b0 = blockIdx.x * chunk;
    const int b1 = min(E, b0 + chunk);
    if (b0 >= b1) return;
    for (int t = threadIdx.x; t < NBK; t += blockDim.x) lcnt[t] = 0;
    __syncthreads();
    // ---- phase 1: count dst buckets (dst stream only, nt int4)
    for (int base = b0 + threadIdx.x * 4; base < b1; base += blockDim.x * 4) {
        if (base + 4 <= b1) {
            iv4 d4 = __builtin_nontemporal_load((const iv4*)(ei + (size_t)E + base));
            atomicAdd(&lcnt[(uint32_t)d4.x >> BK_SHIFT], 1u);
            atomicAdd(&lcnt[(uint32_t)d4.y >> BK_SHIFT], 1u);
            atomicAdd(&lcnt[(uint32_t)d4.z >> BK_SHIFT], 1u);
            atomicAdd(&lcnt[(uint32_t)d4.w >> BK_SHIFT], 1u);
        } else {
            for (int j = 0; j < b1 - base; ++j)
                atomicAdd(&lcnt[(uint32_t)ei[(size_t)E + base + j] >> BK_SHIFT], 1u);
        }
    }
    __syncthreads();
    // ---- reserve per-(part,bucket) ranges
    for (int t = threadIdx.x; t < NBK; t += blockDim.x) {
        uint32_t c = lcnt[t];
        lbase[t] = c ? atomicAdd(&cursor[part * NBK + t], c) : 0u;
        lcnt[t] = 0;
    }
    __syncthreads();
    // ---- phase 2: place records
    for (int base = b0 + threadIdx.x * 4; base < b1; base += blockDim.x * 4) {
        int ss[4], dd[4], m;
        if (base + 4 <= b1) {
            iv4 s4 = __builtin_nontemporal_load((const iv4*)(ei + base));
            iv4 d4 = __builtin_nontemporal_load((const iv4*)(ei + (size_t)E + base));
            ss[0]=s4.x; ss[1]=s4.y; ss[2]=s4.z; ss[3]=s4.w;
            dd[0]=d4.x; dd[1]=d4.y; dd[2]=d4.z; dd[3]=d4.w;
            m = 4;
        } else {
            m = b1 - base;
            for (int j = 0; j < m; ++j) {
                ss[j] = ei[base + j];
                dd[j] = ei[(size_t)E + base + j];
            }
        }
        for (int j = 0; j < m; ++j) {
            uint32_t bk = (uint32_t)dd[j] >> BK_SHIFT;
            uint32_t rec = ((uint32_t)(dd[j] & (BK_NODES - 1)) << 20) | (uint32_t)ss[j];
            uint32_t l = atomicAdd(&lcnt[bk], 1u);
            uint32_t idx = lbase[bk] + l;
            if (idx < PCAP) {
                binned[((size_t)part * NBK + bk) * PCAP + idx] = rec;
            } else {
                unsigned int o = atomicAdd(ovf_cnt, 1u);
                if (o < OVFCAP) ovf[o] = ((unsigned long long)bk << 32) | rec;
            }
        }
    }
}

// 2b. per-bucket LDS multiset accumulation over 8 partition segments + fused
//     node-hash + fused hash-table insert; memoizes each node's final slot.
//     table slot = (h & SIGMASK) | node; atomicMin keeps min node per group.
__global__ __launch_bounds__(1024)
void k_accum(const uint32_t* __restrict__ binned, const uint32_t* __restrict__ cursor,
             const unsigned long long* __restrict__ ovf, const unsigned int* __restrict__ ovf_cnt,
             const uint64_t* __restrict__ lab, unsigned long long* __restrict__ table,
             uint32_t* __restrict__ slot32, int N, int NBK) {
    __shared__ unsigned long long s1[BK_NODES];
    __shared__ unsigned long long s2[BK_NODES];
    int b = blockIdx.x;
    for (int t = threadIdx.x; t < BK_NODES; t += blockDim.x) { s1[t] = 0ULL; s2[t] = 0ULL; }
    __syncthreads();
    for (int p = 0; p < NPART; ++p) {
        uint32_t cnt = cursor[p * NBK + b];
        if (cnt > PCAP) cnt = PCAP;
        const uint32_t* seg = binned + ((size_t)p * NBK + b) * PCAP;
        for (uint32_t i = threadIdx.x * 4; i < cnt; i += blockDim.x * 4) {
            uint32_t recs[4];
            int m;
            if (i + 4 <= cnt) {
                iv4 r4 = __builtin_nontemporal_load((const iv4*)(seg + i));
                recs[0]=(uint32_t)r4.x; recs[1]=(uint32_t)r4.y;
                recs[2]=(uint32_t)r4.z; recs[3]=(uint32_t)r4.w;
                m = 4;
            } else {
                m = (int)(cnt - i);
                for (int j = 0; j < m; ++j) recs[j] = seg[i + j];
            }
            for (int j = 0; j < m; ++j) {
                uint64_t nl = lab[recs[j] & 0xFFFFFu];
                uint32_t dl = recs[j] >> 20;
                atomicAdd(&s1[dl], (unsigned long long)mix64(nl, KC1, KC2));
                atomicAdd(&s2[dl], (unsigned long long)mix64(nl, KC3, KC4));
            }
        }
    }
    // overflow sweep (normally ovf_cnt == 0)
    uint32_t oc = *ovf_cnt;
    if (oc > OVFCAP) oc = OVFCAP;
    for (uint32_t i = threadIdx.x; i < oc; i += blockDim.x) {
        unsigned long long r = ovf[i];
        if ((uint32_t)(r >> 32) == (uint32_t)b) {
            uint32_t rec = (uint32_t)r;
            uint64_t nl = lab[rec & 0xFFFFFu];
            uint32_t dl = rec >> 20;
            atomicAdd(&s1[dl], (unsigned long long)mix64(nl, KC1, KC2));
            atomicAdd(&s2[dl], (unsigned long long)mix64(nl, KC3, KC4));
        }
    }
    __syncthreads();
    int node0 = b << BK_SHIFT;
    for (int t = threadIdx.x; t < BK_NODES; t += blockDim.x) {
        int node = node0 + t;
        if (node < N) {
            uint64_t l = lab[node];
            uint64_t h = mix64(l * KC3 + (uint64_t)s1[t], KC1, KC2)
                       ^ mix64((uint64_t)s2[t] + l, KC3, KC4);
            // ---- fused insert: claim slot or min-merge into same-sig slot
            uint64_t entry = (h & SIGMASK) | (uint64_t)(uint32_t)node;
            uint32_t slot = tslot(h);
            for (;;) {
                unsigned long long cur = table[slot];
                if (cur == KEMPTY) {
                    unsigned long long prev =
                        atomicCAS(&table[slot], KEMPTY, (unsigned long long)entry);
                    if (prev == KEMPTY) break;
                    cur = prev;   // lost race: resolve with the true value
                }
                if ((cur & SIGMASK) == (entry & SIGMASK)) {
                    atomicMin(&table[slot], (unsigned long long)entry);
                    break;
                }
                slot = (slot + 1u) & TMASK;
            }
            slot32[node] = slot;
        }
    }
}

// 4b+4c fused: probe-free lookup (my memoized slot holds my group's min idx),
//     flag = (rep==i), per-1024-block inclusive scan of flags + block sums.
__global__ __launch_bounds__(1024)
void k_lookup_scan(const uint32_t* __restrict__ slot32, const unsigned long long* __restrict__ table,
                   unsigned int* __restrict__ rep, int* __restrict__ incl,
                   int* __restrict__ bsums, int N) {
    __shared__ int sm[1024];
    int tid = threadIdx.x;
    int i = blockIdx.x * 1024 + tid;
    int v = 0;
    if (i < N) {
        unsigned long long e = table[slot32[i]];
        unsigned int r = (unsigned int)(e & 0xFFFFFu);
        rep[i] = r;
        v = (r == (unsigned int)i) ? 1 : 0;
    }
    sm[tid] = v;
    __syncthreads();
    for (int off = 1; off < 1024; off <<= 1) {
        int t = (tid >= off) ? sm[tid - off] : 0;
        __syncthreads();
        sm[tid] += t;
        __syncthreads();
    }
    if (i < N) incl[i] = sm[tid];
    if (tid == 1023) bsums[blockIdx.x] = sm[1023];
}

// 4d. exclusive scan of block sums (NB <= 1024, single block)
__global__ void k_scan2(const int* __restrict__ bsums, int* __restrict__ boffs, int NB) {
    __shared__ int sm[1024];
    int tid = threadIdx.x;
    int v = (tid < NB) ? bsums[tid] : 0;
    sm[tid] = v;
    __syncthreads();
    for (int off = 1; off < 1024; off <<= 1) {
        int t = (tid >= off) ? sm[tid - off] : 0;
        __syncthreads();
        sm[tid] += t;
        __syncthreads();
    }
    if (tid < NB) boffs[tid] = sm[tid] - v;  // exclusive
}

// 5. out[i] = exclusive-prefix-of-flags at rep[i]
__global__ void k_final(const unsigned int* __restrict__ rep, const int* __restrict__ incl,
                        const int* __restrict__ boffs, int* __restrict__ out, int N) {
    int i = blockIdx.x * blockDim.x + threadIdx.x;
    if (i >= N) return;
    unsigned int r = rep[i];
    out[i] = incl[r] + boffs[r >> 10] - 1;
}

extern "C" void kernel_launch(void* const* d_in, const int* in_sizes, int n_in,
                              void* d_out, int out_size, void* d_ws, size_t ws_size,
                              hipStream_t stream) {
    const int* x  = (const int*)d_in[0];
    const int* ei = (const int*)d_in[1];
    int N = out_size;
    int F = in_sizes[0] / N;
    int E = in_sizes[1] / 2;
    int* out = (int*)d_out;

    int NBK = (N + BK_NODES - 1) >> BK_SHIFT;  // 245 for N=1e6

    // workspace layout; ~95.6 MB total (<= 96.05 MB proven in round 2)
    char* w = (char*)d_ws;
    uint64_t* lab = (uint64_t*)w;                        w += (size_t)N * 8;       // 8 MB
    uint32_t* slot32 = (uint32_t*)w;                     w += (size_t)N * 4;       // 4 MB
    uint32_t* cursor = (uint32_t*)w;                     w += (size_t)NPART * NBK_MAX * 4;
    unsigned int* ovf_cnt = (unsigned int*)w;            w += 16;
    unsigned long long* ovf = (unsigned long long*)w;    w += (size_t)OVFCAP * 8;  // 128 KB
    unsigned long long* table = (unsigned long long*)w;  w += (size_t)TBL * 8;     // 16 MB (live thru lookup)
    uint32_t* binned = (uint32_t*)w;                     // NPART*NBK*PCAP*4 (~66.7 MB)
    // rep/incl/bsums/boffs dead until after k_accum -> alias the binned region
    char* a = (char*)binned;
    unsigned int* rep = (unsigned int*)a;                a += (size_t)N * 4;
    int* incl = (int*)a;                                 a += (size_t)N * 4;
    int* bsums = (int*)a;                                a += 1024 * 4;
    int* boffs = (int*)a;                                a += 1024 * 4;

    int nb = (N + 255) / 256;
    int NB = (N + 1023) / 1024;
    int SCB = 256;                                // 1 block/CU, part = blockIdx&7
    int chunk = ((E + SCB - 1) / SCB + 3) & ~3;   // 62500 for E=16M

    (void)hipMemsetAsync(cursor, 0, (size_t)NPART * NBK_MAX * 4 + 16, stream);  // + ovf_cnt
    (void)hipMemsetAsync(table, 0xFF, (size_t)TBL * 8, stream);
    k_lab<<<nb, 256, 0, stream>>>(x, lab, N, F);
    k_scatter<<<SCB, 1024, 0, stream>>>(ei, binned, cursor, ovf, ovf_cnt, E, NBK, chunk);
    k_accum<<<NBK, 1024, 0, stream>>>(binned, cursor, ovf, ovf_cnt, lab, table, slot32, N, NBK);
    k_lookup_scan<<<NB, 1024, 0, stream>>>(slot32, table, rep, incl, bsums, N);
    k_scan2<<<1, 1024, 0, stream>>>(bsums, boffs, NB);
    k_final<<<nb, 256, 0, stream>>>(rep, incl, boffs, out, N);
}